// Round 16
// baseline (40.815 us; speedup 1.0000x reference)
//
#include <hip/hip_runtime.h>
#include <cstdint>
#include <cstddef>

// ===========================================================================
// DIAGNOSTIC ROUND: grid replicated x3 (benign identical-value race) so the
// ~19us fis_kernel dispatch lasts ~57us and surfaces in rocprof top-5 above
// the harness's 40us fill kernels. Base kernel = best-so-far (R10, 18.9us).
// ===========================================================================

namespace cx {

constexpr uint32_t hashmix(uint32_t value, uint32_t& hc) {
    value ^= hc; hc *= 0x931e8875u; value *= hc; value ^= value >> 16; return value;
}
constexpr uint32_t mixf(uint32_t x, uint32_t y) {
    uint32_t r = x * 0xca01f9ddu - y * 0x4973f715u; r ^= r >> 16; return r;
}

struct Pcg64 {
    unsigned __int128 state{}, inc{};
    bool has_uint32{}; uint32_t uinteger{};
    static constexpr unsigned __int128 mult() {
        return (((unsigned __int128)2549297995355413924ULL) << 64) | 4865540595714422341ULL;
    }
    constexpr void step() { state = state * mult() + inc; }
    constexpr void seed_default0() {
        uint32_t pool[4] = {0, 0, 0, 0};
        uint32_t hc = 0x43b0d7e5u;  // INIT_A
        for (int i = 0; i < 4; ++i) pool[i] = hashmix(0u, hc);
        for (int isrc = 0; isrc < 4; ++isrc)
            for (int idst = 0; idst < 4; ++idst)
                if (isrc != idst) pool[idst] = mixf(pool[idst], hashmix(pool[isrc], hc));
        uint32_t st[8] = {};
        uint32_t hc2 = 0x8b51f9ddu;  // INIT_B
        for (int i = 0; i < 8; ++i) {
            uint32_t dv = pool[i & 3];
            dv ^= hc2; hc2 *= 0x58f38dedu; dv *= hc2; dv ^= dv >> 16;
            st[i] = dv;
        }
        const uint64_t v0 = (uint64_t)st[0] | ((uint64_t)st[1] << 32);
        const uint64_t v1 = (uint64_t)st[2] | ((uint64_t)st[3] << 32);
        const uint64_t v2 = (uint64_t)st[4] | ((uint64_t)st[5] << 32);
        const uint64_t v3 = (uint64_t)st[6] | ((uint64_t)st[7] << 32);
        const unsigned __int128 s = (((unsigned __int128)v0) << 64) | v1;
        const unsigned __int128 i_ = (((unsigned __int128)v2) << 64) | v3;
        state = 0; inc = (i_ << 1) | 1;
        step(); state += s; step();
        has_uint32 = false; uinteger = 0;
    }
    constexpr uint64_t next64() {
        step();
        const uint64_t hi = (uint64_t)(state >> 64), lo = (uint64_t)state;
        const uint64_t x = hi ^ lo;
        const unsigned rot = (unsigned)(state >> 122);
        return (x >> rot) | (x << ((64u - rot) & 63u));
    }
    constexpr uint32_t next32() {
        if (has_uint32) { has_uint32 = false; return uinteger; }
        const uint64_t n = next64();
        has_uint32 = true; uinteger = (uint32_t)(n >> 32);
        return (uint32_t)n;
    }
    constexpr uint32_t bounded_lemire32(uint32_t rng) {
        const uint32_t rng_excl = rng + 1u;
        uint64_t m = (uint64_t)next32() * (uint64_t)rng_excl;
        uint32_t leftover = (uint32_t)m;
        if (leftover < rng_excl) {
            const uint32_t threshold = (0xFFFFFFFFu - rng) % rng_excl;
            while (leftover < threshold) {
                m = (uint64_t)next32() * (uint64_t)rng_excl;
                leftover = (uint32_t)m;
            }
        }
        return (uint32_t)(m >> 32);
    }
    constexpr int64_t integers0(int64_t high) {
        const uint64_t rng = (uint64_t)(high - 1);
        if (rng == 0) return 0;  // no RNG consumption
        return (int64_t)bounded_lemire32((uint32_t)rng);
    }
};

constexpr int NTREE = 32, MAXSER = 32, MAXROOT = 32, MAXFAC = 5, MAXSLOT = 12;

struct Plan {
    int nser, nroot, nslot, maxlvl;
    int lvl[MAXSER];
    int slot[MAXSER];
    int nfac[MAXSER];
    int fac[MAXSER][4];
    int rnfac[MAXROOT];
    int rfac[MAXROOT][MAXFAC];
    int rlvl[MAXROOT];
    int tree_root[NTREE];
};

constexpr Plan build_plan() {
    Plan P{};
    unsigned skey[MAXSER] = {}, rkey[MAXROOT] = {};
    P.nser = 1; skey[0] = (2u << 16) | 2u;  // leaf canonical code "10"
    P.nfac[0] = 0;
    P.nroot = 0;

    Pcg64 rng; rng.seed_default0();
    for (int t = 0; t < NTREE; ++t) {
        int par[6] = {0, 0, 0, 0, 0, 0};
        for (int i = 1; i <= 5; ++i) par[i] = (int)rng.integers0(i);
        int ch[6][5] = {}; int nch[6] = {};
        for (int i = 1; i <= 5; ++i) ch[par[i]][nch[par[i]]++] = i;

        int sid[6] = {}; unsigned keyn[6] = {};
        for (int i = 5; i >= 1; --i) {
            const int n = nch[i];
            unsigned ck[5] = {}; int cf[5] = {};
            for (int k = 0; k < n; ++k) { ck[k] = keyn[ch[i][k]]; cf[k] = sid[ch[i][k]]; }
            for (int a = 0; a < n; ++a)
                for (int bq = a + 1; bq < n; ++bq) {
                    if (ck[bq] > ck[a]) { unsigned tmp = ck[a]; ck[a] = ck[bq]; ck[bq] = tmp; }
                    if (cf[bq] < cf[a]) { int tmp = cf[a]; cf[a] = cf[bq]; cf[bq] = tmp; }
                }
            unsigned bits = 1u, len = 1u;
            for (int k = 0; k < n; ++k) { bits = (bits << (ck[k] >> 16)) | (ck[k] & 0xffffu); len += ck[k] >> 16; }
            bits <<= 1; len += 1;
            const unsigned key = (len << 16) | bits;
            keyn[i] = key;
            int id = -1;
            for (int q = 0; q < P.nser; ++q) if (skey[q] == key) { id = q; break; }
            if (id < 0) {
                id = P.nser++;
                skey[id] = key; P.nfac[id] = n;
                for (int k = 0; k < n; ++k) P.fac[id][k] = cf[k];
            }
            sid[i] = id;
        }
        {   // root shape
            const int n = nch[0];
            unsigned ck[5] = {}; int cf[5] = {};
            for (int k = 0; k < n; ++k) { ck[k] = keyn[ch[0][k]]; cf[k] = sid[ch[0][k]]; }
            for (int a = 0; a < n; ++a)
                for (int bq = a + 1; bq < n; ++bq) {
                    if (ck[bq] > ck[a]) { unsigned tmp = ck[a]; ck[a] = ck[bq]; ck[bq] = tmp; }
                    if (cf[bq] < cf[a]) { int tmp = cf[a]; cf[a] = cf[bq]; cf[bq] = tmp; }
                }
            unsigned bits = 1u, len = 1u;
            for (int k = 0; k < n; ++k) { bits = (bits << (ck[k] >> 16)) | (ck[k] & 0xffffu); len += ck[k] >> 16; }
            bits <<= 1; len += 1;
            const unsigned key = (len << 16) | bits;
            int id = -1;
            for (int q = 0; q < P.nroot; ++q) if (rkey[q] == key) { id = q; break; }
            if (id < 0) {
                id = P.nroot++;
                rkey[id] = key; P.rnfac[id] = n;
                for (int k = 0; k < n; ++k) P.rfac[id][k] = cf[k];
            }
            P.tree_root[t] = id;
        }
    }
    P.lvl[0] = 0; P.maxlvl = 0;
    for (int s = 1; s < P.nser; ++s) {
        int m = 0;
        for (int k = 0; k < P.nfac[s]; ++k) { const int l = P.lvl[P.fac[s][k]]; if (l > m) m = l; }
        P.lvl[s] = m + 1;
        if (m + 1 > P.maxlvl) P.maxlvl = m + 1;
    }
    for (int r = 0; r < P.nroot; ++r) {
        int m = 0;
        for (int k = 0; k < P.rnfac[r]; ++k) { const int l = P.lvl[P.rfac[r][k]]; if (l > m) m = l; }
        P.rlvl[r] = m;
    }
    int last[MAXSER] = {};
    for (int s = 0; s < P.nser; ++s) last[s] = 0;
    for (int s = 1; s < P.nser; ++s)
        for (int k = 0; k < P.nfac[s]; ++k) { const int f = P.fac[s][k]; if (P.lvl[s] > last[f]) last[f] = P.lvl[s]; }
    for (int r = 0; r < P.nroot; ++r)
        for (int k = 0; k < P.rnfac[r]; ++k) { const int f = P.rfac[r][k]; if (P.rlvl[r] > last[f]) last[f] = P.rlvl[r]; }
    int free_at[MAXSLOT] = {};
    for (int q = 0; q < MAXSLOT; ++q) free_at[q] = -1000;
    P.nslot = 0;
    for (int L = 0; L <= P.maxlvl; ++L)
        for (int s = 0; s < P.nser; ++s) {
            if (P.lvl[s] != L) continue;
            int pick = -1;
            for (int q = 0; q < MAXSLOT; ++q) if (free_at[q] <= L) { pick = q; break; }
            P.slot[s] = pick;
            free_at[pick] = last[s] + 1;
            if (pick + 1 > P.nslot) P.nslot = pick + 1;
        }
    return P;
}

constexpr Plan PL = build_plan();
static_assert(PL.nser <= MAXSER && PL.nroot <= MAXROOT, "plan overflow");
static_assert(PL.nslot <= MAXSLOT && PL.maxlvl <= 9, "plan overflow");
static_assert(PL.nslot >= 1 && PL.nser >= 1 && PL.nroot >= 1, "plan degenerate");

}  // namespace cx

// ===========================================================================
// DPP wave scan (gfx9 canonical). Validated on-HW rounds 3-15.
// ===========================================================================
template <int CTRL, int RM>
__device__ __forceinline__ float dppmov(float x) {
    return __builtin_bit_cast(float,
        __builtin_amdgcn_update_dpp(0, __builtin_bit_cast(int, x), CTRL, RM, 0xf, false));
}
__device__ __forceinline__ float wave_incl_scan(float v) {
    v += dppmov<0x111, 0xf>(v);
    v += dppmov<0x112, 0xf>(v);
    v += dppmov<0x114, 0xf>(v);
    v += dppmov<0x118, 0xf>(v);
    v += dppmov<0x142, 0xa>(v);  // row_bcast:15 -> rows 1,3
    v += dppmov<0x143, 0xc>(v);  // row_bcast:31 -> rows 2,3
    return v;                    // inclusive; lane63 = wave total
}

struct OutMap { unsigned char m[32]; };

typedef float v2f __attribute__((ext_vector_type(2)));

// ===========================================================================
// Best-so-far kernel (R10 bench: 18.9us): 256 threads x 16 elems as 8x float2,
// FMA-fused chains, inclusive-store + descending shift. Replicated x3 via
// grid for this diagnostic round (bc = blockIdx.x & 2047).
// ===========================================================================
#define THREADS 256
#define VECN 8      // 8 x float2 = 16 elems
#define NWAVE 4
#define REPL 3

__global__ __launch_bounds__(THREADS) void fis_kernel(const float* __restrict__ x,
                                                      const float* __restrict__ alphas,
                                                      float* __restrict__ out,
                                                      const OutMap om) {
    using cx::PL;
    constexpr int NSER = PL.nser, NROOT = PL.nroot, NSLOT = PL.nslot, MAXL = PL.maxlvl;

    const int tid = threadIdx.x;
    const int lane = tid & 63;
    const int wv = tid >> 6;
    const int bc = blockIdx.x & 2047;   // 3 replicas compute identical values
    const int b = bc >> 7;              // CH = 128
    const int c = bc & 127;

    __shared__ float s_w[NSER + NROOT][NWAVE];

    v2f xr[VECN];
    {
        const float4* xv = reinterpret_cast<const float4*>(
            x + (size_t)bc * 4096 + (size_t)tid * 16);
#pragma unroll
        for (int j = 0; j < 4; ++j) {
            const float4 v = xv[j];
            xr[2 * j + 0] = v2f{v.x, v.y};
            xr[2 * j + 1] = v2f{v.z, v.w};
        }
    }

    v2f S[NSLOT][VECN];     // compile-time indexed after unroll -> registers
    float wex[cx::MAXSER];  // per-scan carried scalar (exclusive-in-wave offset)
    float tot[cx::MAXSER];

#pragma unroll
    for (int L = 0; L <= MAXL; ++L) {
        // ---- pre-phase: scans at level L ----
#pragma unroll
        for (int s = 0; s < NSER; ++s) {
            if (PL.lvl[s] != L) continue;
            const int ds = PL.slot[s];
            float run = 0.f;
            if (PL.nfac[s] == 0) {
                // leaf series: inclusive local cumsum of x (scalar chain, SSA)
#pragma unroll
                for (int j = 0; j < VECN; ++j) {
                    const float a = run + xr[j].x;
                    const float b2 = a + xr[j].y;
                    S[ds][j] = v2f{a, b2};
                    run = b2;
                }
            } else {
                v2f v[VECN];
#pragma unroll
                for (int j = 0; j < VECN; ++j) v[j] = xr[j];
#pragma unroll
                for (int k = 0; k < 3; ++k) {          // all factors but the last
                    if (k < PL.nfac[s] - 1) {
                        const int fs = PL.slot[PL.fac[s][k]];
#pragma unroll
                        for (int j = 0; j < VECN; ++j) v[j] *= S[fs][j];
                    }
                }
                const int fl = PL.slot[PL.fac[s][PL.nfac[s] - 1]];
#pragma unroll
                for (int j = 0; j < VECN; ++j) {       // fused scalar chain
                    const float a = __builtin_fmaf(v[j].x, S[fl][j].x, run);
                    const float b2 = __builtin_fmaf(v[j].y, S[fl][j].y, a);
                    S[ds][j] = v2f{a, b2};             // inclusive local
                    run = b2;
                }
            }
            tot[s] = run;
            const float wi = wave_incl_scan(run);
            if (lane == 63) s_w[s][wv] = wi;           // wave total
            wex[s] = wi - run;                         // exclusive within wave
        }
        __syncthreads();
        // ---- post-phase: exclusive = base + inclusive[j-1] (descending shift) ----
#pragma unroll
        for (int s = 0; s < NSER; ++s) {
            if (PL.lvl[s] != L) continue;
            const int ds = PL.slot[s];
            float base = wex[s];
#pragma unroll
            for (int k = 0; k < NWAVE - 1; ++k)
                if (k < wv) base += s_w[s][k];
#pragma unroll
            for (int j = VECN - 1; j >= 1; --j) {
                S[ds][j].y = base + S[ds][j].x;
                S[ds][j].x = base + S[ds][j - 1].y;
            }
            S[ds][0].y = base + S[ds][0].x;
            S[ds][0].x = base;
        }
        // ---- root reduces whose deepest factor is level L ----
#pragma unroll
        for (int r = 0; r < NROOT; ++r) {
            if (PL.rlvl[r] != L) continue;
            v2f v[VECN];
#pragma unroll
            for (int j = 0; j < VECN; ++j) v[j] = xr[j];
#pragma unroll
            for (int k = 0; k < 4; ++k) {              // all factors but the last
                if (k < PL.rnfac[r] - 1) {
                    const int fs = PL.slot[PL.rfac[r][k]];
#pragma unroll
                    for (int j = 0; j < VECN; ++j) v[j] *= S[fs][j];
                }
            }
            const int fl = PL.slot[PL.rfac[r][PL.rnfac[r] - 1]];
            v2f acc = v2f{0.f, 0.f};
#pragma unroll
            for (int j = 0; j < VECN; ++j) acc += v[j] * S[fl][j];
            const float wr = wave_incl_scan(acc.x + acc.y);
            if (lane == 63) s_w[NSER + r][wv] = wr;    // per-wave partial
        }
    }

    __syncthreads();
    if (tid < 32) {
        const int rid = om.m[tid];
        float T = 0.f;
#pragma unroll
        for (int k = 0; k < NWAVE; ++k) T += s_w[NSER + rid][k];
        const float* ap = alphas + tid * 768 + c;  // alphas[tree, i, c] : [32,6,128]
        const float aprod = ap[0] * ap[128] * ap[256] * ap[384] * ap[512] * ap[640];
        out[(((size_t)b << 5) + (size_t)tid) * 128 + c] = aprod * T;
    }
}

// ===========================================================================
extern "C" void kernel_launch(void* const* d_in, const int* in_sizes, int n_in,
                              void* d_out, int out_size, void* d_ws, size_t ws_size,
                              hipStream_t stream) {
    const float* x = (const float*)d_in[0];       // [16,128,4096] f32
    const float* alphas = (const float*)d_in[1];  // [32,6,128]    f32
    float* out = (float*)d_out;                   // [16,32,128]   f32

    OutMap om;
    for (int t = 0; t < cx::NTREE; ++t) om.m[t] = (unsigned char)cx::PL.tree_root[t];

    fis_kernel<<<dim3(16 * 128 * REPL), dim3(THREADS), 0, stream>>>(x, alphas, out, om);
}

// Round 18
// 22.519 us; speedup vs baseline: 1.8125x; 1.8125x over previous
//
#include <hip/hip_runtime.h>
#include <cstdint>
#include <cstddef>

// ===========================================================================
// R16 diagnostic findings (x3-replica rocprof, first real counters):
//   VGPR=84 (occupancy never the limiter; 4 waves/SIMD class), VALUBusy=65%,
//   ~1500 instr/wave (estimate was right), conflicts 0, and dur = 13.2us
//   compute + ~5.5us EXPOSED x-stream (33.5MB @ 6.3TB/s = 5.3us; x3 shared
//   x via L3: FETCH 47.7MB not 100MB). This round hides the stream:
//   each block owns TWO rows; row-1 loads issue at kernel start and stay
//   in flight (vmcnt) under row-0's compute. Compute structure = R10 best.
// ===========================================================================

namespace cx {

constexpr uint32_t hashmix(uint32_t value, uint32_t& hc) {
    value ^= hc; hc *= 0x931e8875u; value *= hc; value ^= value >> 16; return value;
}
constexpr uint32_t mixf(uint32_t x, uint32_t y) {
    uint32_t r = x * 0xca01f9ddu - y * 0x4973f715u; r ^= r >> 16; return r;
}

struct Pcg64 {
    unsigned __int128 state{}, inc{};
    bool has_uint32{}; uint32_t uinteger{};
    static constexpr unsigned __int128 mult() {
        return (((unsigned __int128)2549297995355413924ULL) << 64) | 4865540595714422341ULL;
    }
    constexpr void step() { state = state * mult() + inc; }
    constexpr void seed_default0() {
        uint32_t pool[4] = {0, 0, 0, 0};
        uint32_t hc = 0x43b0d7e5u;  // INIT_A
        for (int i = 0; i < 4; ++i) pool[i] = hashmix(0u, hc);
        for (int isrc = 0; isrc < 4; ++isrc)
            for (int idst = 0; idst < 4; ++idst)
                if (isrc != idst) pool[idst] = mixf(pool[idst], hashmix(pool[isrc], hc));
        uint32_t st[8] = {};
        uint32_t hc2 = 0x8b51f9ddu;  // INIT_B
        for (int i = 0; i < 8; ++i) {
            uint32_t dv = pool[i & 3];
            dv ^= hc2; hc2 *= 0x58f38dedu; dv *= hc2; dv ^= dv >> 16;
            st[i] = dv;
        }
        const uint64_t v0 = (uint64_t)st[0] | ((uint64_t)st[1] << 32);
        const uint64_t v1 = (uint64_t)st[2] | ((uint64_t)st[3] << 32);
        const uint64_t v2 = (uint64_t)st[4] | ((uint64_t)st[5] << 32);
        const uint64_t v3 = (uint64_t)st[6] | ((uint64_t)st[7] << 32);
        const unsigned __int128 s = (((unsigned __int128)v0) << 64) | v1;
        const unsigned __int128 i_ = (((unsigned __int128)v2) << 64) | v3;
        state = 0; inc = (i_ << 1) | 1;
        step(); state += s; step();
        has_uint32 = false; uinteger = 0;
    }
    constexpr uint64_t next64() {
        step();
        const uint64_t hi = (uint64_t)(state >> 64), lo = (uint64_t)state;
        const uint64_t x = hi ^ lo;
        const unsigned rot = (unsigned)(state >> 122);
        return (x >> rot) | (x << ((64u - rot) & 63u));
    }
    constexpr uint32_t next32() {
        if (has_uint32) { has_uint32 = false; return uinteger; }
        const uint64_t n = next64();
        has_uint32 = true; uinteger = (uint32_t)(n >> 32);
        return (uint32_t)n;
    }
    constexpr uint32_t bounded_lemire32(uint32_t rng) {
        const uint32_t rng_excl = rng + 1u;
        uint64_t m = (uint64_t)next32() * (uint64_t)rng_excl;
        uint32_t leftover = (uint32_t)m;
        if (leftover < rng_excl) {
            const uint32_t threshold = (0xFFFFFFFFu - rng) % rng_excl;
            while (leftover < threshold) {
                m = (uint64_t)next32() * (uint64_t)rng_excl;
                leftover = (uint32_t)m;
            }
        }
        return (uint32_t)(m >> 32);
    }
    constexpr int64_t integers0(int64_t high) {
        const uint64_t rng = (uint64_t)(high - 1);
        if (rng == 0) return 0;  // no RNG consumption
        return (int64_t)bounded_lemire32((uint32_t)rng);
    }
};

constexpr int NTREE = 32, MAXSER = 32, MAXROOT = 32, MAXFAC = 5, MAXSLOT = 12;

struct Plan {
    int nser, nroot, nslot, maxlvl;
    int lvl[MAXSER];
    int slot[MAXSER];
    int nfac[MAXSER];
    int fac[MAXSER][4];
    int rnfac[MAXROOT];
    int rfac[MAXROOT][MAXFAC];
    int rlvl[MAXROOT];
    int tree_root[NTREE];
};

constexpr Plan build_plan() {
    Plan P{};
    unsigned skey[MAXSER] = {}, rkey[MAXROOT] = {};
    P.nser = 1; skey[0] = (2u << 16) | 2u;  // leaf canonical code "10"
    P.nfac[0] = 0;
    P.nroot = 0;

    Pcg64 rng; rng.seed_default0();
    for (int t = 0; t < NTREE; ++t) {
        int par[6] = {0, 0, 0, 0, 0, 0};
        for (int i = 1; i <= 5; ++i) par[i] = (int)rng.integers0(i);
        int ch[6][5] = {}; int nch[6] = {};
        for (int i = 1; i <= 5; ++i) ch[par[i]][nch[par[i]]++] = i;

        int sid[6] = {}; unsigned keyn[6] = {};
        for (int i = 5; i >= 1; --i) {
            const int n = nch[i];
            unsigned ck[5] = {}; int cf[5] = {};
            for (int k = 0; k < n; ++k) { ck[k] = keyn[ch[i][k]]; cf[k] = sid[ch[i][k]]; }
            for (int a = 0; a < n; ++a)
                for (int bq = a + 1; bq < n; ++bq) {
                    if (ck[bq] > ck[a]) { unsigned tmp = ck[a]; ck[a] = ck[bq]; ck[bq] = tmp; }
                    if (cf[bq] < cf[a]) { int tmp = cf[a]; cf[a] = cf[bq]; cf[bq] = tmp; }
                }
            unsigned bits = 1u, len = 1u;
            for (int k = 0; k < n; ++k) { bits = (bits << (ck[k] >> 16)) | (ck[k] & 0xffffu); len += ck[k] >> 16; }
            bits <<= 1; len += 1;
            const unsigned key = (len << 16) | bits;
            keyn[i] = key;
            int id = -1;
            for (int q = 0; q < P.nser; ++q) if (skey[q] == key) { id = q; break; }
            if (id < 0) {
                id = P.nser++;
                skey[id] = key; P.nfac[id] = n;
                for (int k = 0; k < n; ++k) P.fac[id][k] = cf[k];
            }
            sid[i] = id;
        }
        {   // root shape
            const int n = nch[0];
            unsigned ck[5] = {}; int cf[5] = {};
            for (int k = 0; k < n; ++k) { ck[k] = keyn[ch[0][k]]; cf[k] = sid[ch[0][k]]; }
            for (int a = 0; a < n; ++a)
                for (int bq = a + 1; bq < n; ++bq) {
                    if (ck[bq] > ck[a]) { unsigned tmp = ck[a]; ck[a] = ck[bq]; ck[bq] = tmp; }
                    if (cf[bq] < cf[a]) { int tmp = cf[a]; cf[a] = cf[bq]; cf[bq] = tmp; }
                }
            unsigned bits = 1u, len = 1u;
            for (int k = 0; k < n; ++k) { bits = (bits << (ck[k] >> 16)) | (ck[k] & 0xffffu); len += ck[k] >> 16; }
            bits <<= 1; len += 1;
            const unsigned key = (len << 16) | bits;
            int id = -1;
            for (int q = 0; q < P.nroot; ++q) if (rkey[q] == key) { id = q; break; }
            if (id < 0) {
                id = P.nroot++;
                rkey[id] = key; P.rnfac[id] = n;
                for (int k = 0; k < n; ++k) P.rfac[id][k] = cf[k];
            }
            P.tree_root[t] = id;
        }
    }
    P.lvl[0] = 0; P.maxlvl = 0;
    for (int s = 1; s < P.nser; ++s) {
        int m = 0;
        for (int k = 0; k < P.nfac[s]; ++k) { const int l = P.lvl[P.fac[s][k]]; if (l > m) m = l; }
        P.lvl[s] = m + 1;
        if (m + 1 > P.maxlvl) P.maxlvl = m + 1;
    }
    for (int r = 0; r < P.nroot; ++r) {
        int m = 0;
        for (int k = 0; k < P.rnfac[r]; ++k) { const int l = P.lvl[P.rfac[r][k]]; if (l > m) m = l; }
        P.rlvl[r] = m;
    }
    int last[MAXSER] = {};
    for (int s = 0; s < P.nser; ++s) last[s] = 0;
    for (int s = 1; s < P.nser; ++s)
        for (int k = 0; k < P.nfac[s]; ++k) { const int f = P.fac[s][k]; if (P.lvl[s] > last[f]) last[f] = P.lvl[s]; }
    for (int r = 0; r < P.nroot; ++r)
        for (int k = 0; k < P.rnfac[r]; ++k) { const int f = P.rfac[r][k]; if (P.rlvl[r] > last[f]) last[f] = P.rlvl[r]; }
    int free_at[MAXSLOT] = {};
    for (int q = 0; q < MAXSLOT; ++q) free_at[q] = -1000;
    P.nslot = 0;
    for (int L = 0; L <= P.maxlvl; ++L)
        for (int s = 0; s < P.nser; ++s) {
            if (P.lvl[s] != L) continue;
            int pick = -1;
            for (int q = 0; q < MAXSLOT; ++q) if (free_at[q] <= L) { pick = q; break; }
            P.slot[s] = pick;
            free_at[pick] = last[s] + 1;
            if (pick + 1 > P.nslot) P.nslot = pick + 1;
        }
    return P;
}

constexpr Plan PL = build_plan();
static_assert(PL.nser <= MAXSER && PL.nroot <= MAXROOT, "plan overflow");
static_assert(PL.nslot <= MAXSLOT && PL.maxlvl <= 9, "plan overflow");
static_assert(PL.nslot >= 1 && PL.nser >= 1 && PL.nroot >= 1, "plan degenerate");

}  // namespace cx

// ===========================================================================
// DPP wave scan (gfx9 canonical). Validated on-HW rounds 3-16.
// ===========================================================================
template <int CTRL, int RM>
__device__ __forceinline__ float dppmov(float x) {
    return __builtin_bit_cast(float,
        __builtin_amdgcn_update_dpp(0, __builtin_bit_cast(int, x), CTRL, RM, 0xf, false));
}
__device__ __forceinline__ float wave_incl_scan(float v) {
    v += dppmov<0x111, 0xf>(v);
    v += dppmov<0x112, 0xf>(v);
    v += dppmov<0x114, 0xf>(v);
    v += dppmov<0x118, 0xf>(v);
    v += dppmov<0x142, 0xa>(v);  // row_bcast:15 -> rows 1,3
    v += dppmov<0x143, 0xc>(v);  // row_bcast:31 -> rows 2,3
    return v;                    // inclusive; lane63 = wave total
}

struct OutMap { unsigned char m[32]; };

typedef float v2f __attribute__((ext_vector_type(2)));

// ===========================================================================
// Two rows per block (bc, bc+1024); both x-loads issued up front so row-1's
// loads hide under row-0's compute. Compute structure identical to R10 best
// (18.9us): 8x float2 elems, FMA-fused chains, inclusive-store + shift.
// VGPR est ~100 (84 + 16 for xr1) — same 4-waves/SIMD class.
//
// Known risk under test: __syncthreads drains vmcnt on gfx950, which would
// force xr1's loads to complete at row-0's FIRST barrier (flat result);
// if instead the loads survive in registers (they must be materialized by
// the drain, not re-issued), the HBM latency is already paid early and
// overlapped with the first level's compute (win). Either outcome is
// informative about barrier semantics for this family.
// ===========================================================================
#define THREADS 256
#define VECN 8      // 8 x float2 = 16 elems
#define NWAVE 4

__global__ __launch_bounds__(THREADS) void fis_kernel(const float* __restrict__ x,
                                                      const float* __restrict__ alphas,
                                                      float* __restrict__ out,
                                                      const OutMap om) {
    using cx::PL;
    constexpr int NSER = PL.nser, NROOT = PL.nroot, NSLOT = PL.nslot, MAXL = PL.maxlvl;

    const int tid = threadIdx.x;
    const int lane = tid & 63;
    const int wv = tid >> 6;
    const int bc0 = blockIdx.x;          // rows 0..1023
    const int bc1 = blockIdx.x + 1024;   // rows 1024..2047

    __shared__ float s_w[NSER + NROOT][NWAVE];

    // Issue BOTH rows' loads now; xr0 first so its vmcnt-wait leaves xr1's
    // 4 dwordx4 loads outstanding across row-0's compute (until first drain).
    v2f xr0[VECN], xr1[VECN];
    {
        const float4* xv0 = reinterpret_cast<const float4*>(
            x + (size_t)bc0 * 4096 + (size_t)tid * 16);
        const float4* xv1 = reinterpret_cast<const float4*>(
            x + (size_t)bc1 * 4096 + (size_t)tid * 16);
        float4 a0 = xv0[0], a1 = xv0[1], a2 = xv0[2], a3 = xv0[3];
        float4 b0 = xv1[0], b1 = xv1[1], b2 = xv1[2], b3 = xv1[3];
        xr0[0] = v2f{a0.x, a0.y}; xr0[1] = v2f{a0.z, a0.w};
        xr0[2] = v2f{a1.x, a1.y}; xr0[3] = v2f{a1.z, a1.w};
        xr0[4] = v2f{a2.x, a2.y}; xr0[5] = v2f{a2.z, a2.w};
        xr0[6] = v2f{a3.x, a3.y}; xr0[7] = v2f{a3.z, a3.w};
        xr1[0] = v2f{b0.x, b0.y}; xr1[1] = v2f{b0.z, b0.w};
        xr1[2] = v2f{b1.x, b1.y}; xr1[3] = v2f{b1.z, b1.w};
        xr1[4] = v2f{b2.x, b2.y}; xr1[5] = v2f{b2.z, b2.w};
        xr1[6] = v2f{b3.x, b3.y}; xr1[7] = v2f{b3.z, b3.w};
    }

    v2f S[NSLOT][VECN];     // compile-time indexed after unroll -> registers
    float wex[cx::MAXSER];  // per-scan carried scalar (exclusive-in-wave offset)

    auto do_row = [&](const v2f (&xr)[VECN], const int bc) {
        const int b = bc >> 7;   // CH = 128
        const int c = bc & 127;
#pragma unroll
        for (int L = 0; L <= MAXL; ++L) {
            // ---- pre-phase: scans at level L ----
#pragma unroll
            for (int s = 0; s < NSER; ++s) {
                if (PL.lvl[s] != L) continue;
                const int ds = PL.slot[s];
                float run = 0.f;
                if (PL.nfac[s] == 0) {
                    // leaf series: inclusive local cumsum of x (scalar chain)
#pragma unroll
                    for (int j = 0; j < VECN; ++j) {
                        const float a = run + xr[j].x;
                        const float b2 = a + xr[j].y;
                        S[ds][j] = v2f{a, b2};
                        run = b2;
                    }
                } else {
                    v2f v[VECN];
#pragma unroll
                    for (int j = 0; j < VECN; ++j) v[j] = xr[j];
#pragma unroll
                    for (int k = 0; k < 3; ++k) {      // all factors but the last
                        if (k < PL.nfac[s] - 1) {
                            const int fs = PL.slot[PL.fac[s][k]];
#pragma unroll
                            for (int j = 0; j < VECN; ++j) v[j] *= S[fs][j];
                        }
                    }
                    const int fl = PL.slot[PL.fac[s][PL.nfac[s] - 1]];
#pragma unroll
                    for (int j = 0; j < VECN; ++j) {   // fused scalar chain
                        const float a = __builtin_fmaf(v[j].x, S[fl][j].x, run);
                        const float b2 = __builtin_fmaf(v[j].y, S[fl][j].y, a);
                        S[ds][j] = v2f{a, b2};         // inclusive local
                        run = b2;
                    }
                }
                const float wi = wave_incl_scan(run);
                if (lane == 63) s_w[s][wv] = wi;       // wave total
                wex[s] = wi - run;                     // exclusive within wave
            }
            __syncthreads();
            // ---- post-phase: exclusive = base + inclusive[j-1] ----
#pragma unroll
            for (int s = 0; s < NSER; ++s) {
                if (PL.lvl[s] != L) continue;
                const int ds = PL.slot[s];
                float base = wex[s];
#pragma unroll
                for (int k = 0; k < NWAVE - 1; ++k)
                    if (k < wv) base += s_w[s][k];
#pragma unroll
                for (int j = VECN - 1; j >= 1; --j) {
                    S[ds][j].y = base + S[ds][j].x;
                    S[ds][j].x = base + S[ds][j - 1].y;
                }
                S[ds][0].y = base + S[ds][0].x;
                S[ds][0].x = base;
            }
            // ---- root reduces whose deepest factor is level L ----
#pragma unroll
            for (int r = 0; r < NROOT; ++r) {
                if (PL.rlvl[r] != L) continue;
                v2f v[VECN];
#pragma unroll
                for (int j = 0; j < VECN; ++j) v[j] = xr[j];
#pragma unroll
                for (int k = 0; k < 4; ++k) {          // all factors but the last
                    if (k < PL.rnfac[r] - 1) {
                        const int fs = PL.slot[PL.rfac[r][k]];
#pragma unroll
                        for (int j = 0; j < VECN; ++j) v[j] *= S[fs][j];
                    }
                }
                const int fl = PL.slot[PL.rfac[r][PL.rnfac[r] - 1]];
                v2f acc = v2f{0.f, 0.f};
#pragma unroll
                for (int j = 0; j < VECN; ++j) acc += v[j] * S[fl][j];
                const float wr = wave_incl_scan(acc.x + acc.y);
                if (lane == 63) s_w[NSER + r][wv] = wr;  // per-wave partial
            }
        }

        __syncthreads();
        if (tid < 32) {
            const int rid = om.m[tid];
            float T = 0.f;
#pragma unroll
            for (int k = 0; k < NWAVE; ++k) T += s_w[NSER + rid][k];
            const float* ap = alphas + tid * 768 + c;  // alphas[tree,i,c]:[32,6,128]
            const float aprod = ap[0] * ap[128] * ap[256] * ap[384] * ap[512] * ap[640];
            out[(((size_t)b << 5) + (size_t)tid) * 128 + c] = aprod * T;
        }
        __syncthreads();  // s_w safe for next row (cheap: 2 extra barriers total)
    };

    do_row(xr0, bc0);
    do_row(xr1, bc1);
}

// ===========================================================================
extern "C" void kernel_launch(void* const* d_in, const int* in_sizes, int n_in,
                              void* d_out, int out_size, void* d_ws, size_t ws_size,
                              hipStream_t stream) {
    const float* x = (const float*)d_in[0];       // [16,128,4096] f32
    const float* alphas = (const float*)d_in[1];  // [32,6,128]    f32
    float* out = (float*)d_out;                   // [16,32,128]   f32

    OutMap om;
    for (int t = 0; t < cx::NTREE; ++t) om.m[t] = (unsigned char)cx::PL.tree_root[t];

    fis_kernel<<<dim3(1024), dim3(THREADS), 0, stream>>>(x, alphas, out, om);
}

// Round 19
// 19.083 us; speedup vs baseline: 2.1389x; 1.1801x over previous
//
#include <hip/hip_runtime.h>
#include <cstdint>
#include <cstddef>

// ===========================================================================
// FINAL-BEST (R10: 18.9us). Session ledger:
//  - R4 algorithmic subtree-dedup + constexpr codegen: 163 -> 19.8us (8.2x).
//  - R10 v2f layout + FMA-fused chains: 19.8 -> 18.9us.
//  - Falsified on-HW since: instr count +-25% (flat), barriers 24->0 (worse),
//    VGPR diet (VGPR was 84; flat), chain-depth/2 (worse), 512x8 (worse),
//    2-row stream prefetch (worse: __syncthreads drains vmcnt -> no overlap).
//  - R16 counters: VALUBusy 65%, ~1500 instr/wave, conflicts 0; dur ~=
//    12.3us issue + stream/barrier residue. Cross-block TLP (8 blocks/CU)
//    already overlaps the 5.3us x-stream as well as barrier semantics allow.
// ===========================================================================

namespace cx {

constexpr uint32_t hashmix(uint32_t value, uint32_t& hc) {
    value ^= hc; hc *= 0x931e8875u; value *= hc; value ^= value >> 16; return value;
}
constexpr uint32_t mixf(uint32_t x, uint32_t y) {
    uint32_t r = x * 0xca01f9ddu - y * 0x4973f715u; r ^= r >> 16; return r;
}

struct Pcg64 {
    unsigned __int128 state{}, inc{};
    bool has_uint32{}; uint32_t uinteger{};
    static constexpr unsigned __int128 mult() {
        return (((unsigned __int128)2549297995355413924ULL) << 64) | 4865540595714422341ULL;
    }
    constexpr void step() { state = state * mult() + inc; }
    constexpr void seed_default0() {
        uint32_t pool[4] = {0, 0, 0, 0};
        uint32_t hc = 0x43b0d7e5u;  // INIT_A
        for (int i = 0; i < 4; ++i) pool[i] = hashmix(0u, hc);
        for (int isrc = 0; isrc < 4; ++isrc)
            for (int idst = 0; idst < 4; ++idst)
                if (isrc != idst) pool[idst] = mixf(pool[idst], hashmix(pool[isrc], hc));
        uint32_t st[8] = {};
        uint32_t hc2 = 0x8b51f9ddu;  // INIT_B
        for (int i = 0; i < 8; ++i) {
            uint32_t dv = pool[i & 3];
            dv ^= hc2; hc2 *= 0x58f38dedu; dv *= hc2; dv ^= dv >> 16;
            st[i] = dv;
        }
        const uint64_t v0 = (uint64_t)st[0] | ((uint64_t)st[1] << 32);
        const uint64_t v1 = (uint64_t)st[2] | ((uint64_t)st[3] << 32);
        const uint64_t v2 = (uint64_t)st[4] | ((uint64_t)st[5] << 32);
        const uint64_t v3 = (uint64_t)st[6] | ((uint64_t)st[7] << 32);
        const unsigned __int128 s = (((unsigned __int128)v0) << 64) | v1;
        const unsigned __int128 i_ = (((unsigned __int128)v2) << 64) | v3;
        state = 0; inc = (i_ << 1) | 1;
        step(); state += s; step();
        has_uint32 = false; uinteger = 0;
    }
    constexpr uint64_t next64() {
        step();
        const uint64_t hi = (uint64_t)(state >> 64), lo = (uint64_t)state;
        const uint64_t x = hi ^ lo;
        const unsigned rot = (unsigned)(state >> 122);
        return (x >> rot) | (x << ((64u - rot) & 63u));
    }
    constexpr uint32_t next32() {
        if (has_uint32) { has_uint32 = false; return uinteger; }
        const uint64_t n = next64();
        has_uint32 = true; uinteger = (uint32_t)(n >> 32);
        return (uint32_t)n;
    }
    constexpr uint32_t bounded_lemire32(uint32_t rng) {
        const uint32_t rng_excl = rng + 1u;
        uint64_t m = (uint64_t)next32() * (uint64_t)rng_excl;
        uint32_t leftover = (uint32_t)m;
        if (leftover < rng_excl) {
            const uint32_t threshold = (0xFFFFFFFFu - rng) % rng_excl;
            while (leftover < threshold) {
                m = (uint64_t)next32() * (uint64_t)rng_excl;
                leftover = (uint32_t)m;
            }
        }
        return (uint32_t)(m >> 32);
    }
    constexpr int64_t integers0(int64_t high) {
        const uint64_t rng = (uint64_t)(high - 1);
        if (rng == 0) return 0;  // no RNG consumption
        return (int64_t)bounded_lemire32((uint32_t)rng);
    }
};

constexpr int NTREE = 32, MAXSER = 32, MAXROOT = 32, MAXFAC = 5, MAXSLOT = 12;

struct Plan {
    int nser, nroot, nslot, maxlvl;
    int lvl[MAXSER];
    int slot[MAXSER];
    int nfac[MAXSER];
    int fac[MAXSER][4];
    int rnfac[MAXROOT];
    int rfac[MAXROOT][MAXFAC];
    int rlvl[MAXROOT];
    int tree_root[NTREE];
};

constexpr Plan build_plan() {
    Plan P{};
    unsigned skey[MAXSER] = {}, rkey[MAXROOT] = {};
    P.nser = 1; skey[0] = (2u << 16) | 2u;  // leaf canonical code "10"
    P.nfac[0] = 0;
    P.nroot = 0;

    Pcg64 rng; rng.seed_default0();
    for (int t = 0; t < NTREE; ++t) {
        int par[6] = {0, 0, 0, 0, 0, 0};
        for (int i = 1; i <= 5; ++i) par[i] = (int)rng.integers0(i);
        int ch[6][5] = {}; int nch[6] = {};
        for (int i = 1; i <= 5; ++i) ch[par[i]][nch[par[i]]++] = i;

        int sid[6] = {}; unsigned keyn[6] = {};
        for (int i = 5; i >= 1; --i) {
            const int n = nch[i];
            unsigned ck[5] = {}; int cf[5] = {};
            for (int k = 0; k < n; ++k) { ck[k] = keyn[ch[i][k]]; cf[k] = sid[ch[i][k]]; }
            for (int a = 0; a < n; ++a)
                for (int bq = a + 1; bq < n; ++bq) {
                    if (ck[bq] > ck[a]) { unsigned tmp = ck[a]; ck[a] = ck[bq]; ck[bq] = tmp; }
                    if (cf[bq] < cf[a]) { int tmp = cf[a]; cf[a] = cf[bq]; cf[bq] = tmp; }
                }
            unsigned bits = 1u, len = 1u;
            for (int k = 0; k < n; ++k) { bits = (bits << (ck[k] >> 16)) | (ck[k] & 0xffffu); len += ck[k] >> 16; }
            bits <<= 1; len += 1;
            const unsigned key = (len << 16) | bits;
            keyn[i] = key;
            int id = -1;
            for (int q = 0; q < P.nser; ++q) if (skey[q] == key) { id = q; break; }
            if (id < 0) {
                id = P.nser++;
                skey[id] = key; P.nfac[id] = n;
                for (int k = 0; k < n; ++k) P.fac[id][k] = cf[k];
            }
            sid[i] = id;
        }
        {   // root shape
            const int n = nch[0];
            unsigned ck[5] = {}; int cf[5] = {};
            for (int k = 0; k < n; ++k) { ck[k] = keyn[ch[0][k]]; cf[k] = sid[ch[0][k]]; }
            for (int a = 0; a < n; ++a)
                for (int bq = a + 1; bq < n; ++bq) {
                    if (ck[bq] > ck[a]) { unsigned tmp = ck[a]; ck[a] = ck[bq]; ck[bq] = tmp; }
                    if (cf[bq] < cf[a]) { int tmp = cf[a]; cf[a] = cf[bq]; cf[bq] = tmp; }
                }
            unsigned bits = 1u, len = 1u;
            for (int k = 0; k < n; ++k) { bits = (bits << (ck[k] >> 16)) | (ck[k] & 0xffffu); len += ck[k] >> 16; }
            bits <<= 1; len += 1;
            const unsigned key = (len << 16) | bits;
            int id = -1;
            for (int q = 0; q < P.nroot; ++q) if (rkey[q] == key) { id = q; break; }
            if (id < 0) {
                id = P.nroot++;
                rkey[id] = key; P.rnfac[id] = n;
                for (int k = 0; k < n; ++k) P.rfac[id][k] = cf[k];
            }
            P.tree_root[t] = id;
        }
    }
    P.lvl[0] = 0; P.maxlvl = 0;
    for (int s = 1; s < P.nser; ++s) {
        int m = 0;
        for (int k = 0; k < P.nfac[s]; ++k) { const int l = P.lvl[P.fac[s][k]]; if (l > m) m = l; }
        P.lvl[s] = m + 1;
        if (m + 1 > P.maxlvl) P.maxlvl = m + 1;
    }
    for (int r = 0; r < P.nroot; ++r) {
        int m = 0;
        for (int k = 0; k < P.rnfac[r]; ++k) { const int l = P.lvl[P.rfac[r][k]]; if (l > m) m = l; }
        P.rlvl[r] = m;
    }
    int last[MAXSER] = {};
    for (int s = 0; s < P.nser; ++s) last[s] = 0;
    for (int s = 1; s < P.nser; ++s)
        for (int k = 0; k < P.nfac[s]; ++k) { const int f = P.fac[s][k]; if (P.lvl[s] > last[f]) last[f] = P.lvl[s]; }
    for (int r = 0; r < P.nroot; ++r)
        for (int k = 0; k < P.rnfac[r]; ++k) { const int f = P.rfac[r][k]; if (P.rlvl[r] > last[f]) last[f] = P.rlvl[r]; }
    int free_at[MAXSLOT] = {};
    for (int q = 0; q < MAXSLOT; ++q) free_at[q] = -1000;
    P.nslot = 0;
    for (int L = 0; L <= P.maxlvl; ++L)
        for (int s = 0; s < P.nser; ++s) {
            if (P.lvl[s] != L) continue;
            int pick = -1;
            for (int q = 0; q < MAXSLOT; ++q) if (free_at[q] <= L) { pick = q; break; }
            P.slot[s] = pick;
            free_at[pick] = last[s] + 1;
            if (pick + 1 > P.nslot) P.nslot = pick + 1;
        }
    return P;
}

constexpr Plan PL = build_plan();
static_assert(PL.nser <= MAXSER && PL.nroot <= MAXROOT, "plan overflow");
static_assert(PL.nslot <= MAXSLOT && PL.maxlvl <= 9, "plan overflow");
static_assert(PL.nslot >= 1 && PL.nser >= 1 && PL.nroot >= 1, "plan degenerate");

}  // namespace cx

// ===========================================================================
// DPP wave scan (gfx9 canonical). Validated on-HW rounds 3-18.
// ===========================================================================
template <int CTRL, int RM>
__device__ __forceinline__ float dppmov(float x) {
    return __builtin_bit_cast(float,
        __builtin_amdgcn_update_dpp(0, __builtin_bit_cast(int, x), CTRL, RM, 0xf, false));
}
__device__ __forceinline__ float wave_incl_scan(float v) {
    v += dppmov<0x111, 0xf>(v);
    v += dppmov<0x112, 0xf>(v);
    v += dppmov<0x114, 0xf>(v);
    v += dppmov<0x118, 0xf>(v);
    v += dppmov<0x142, 0xa>(v);  // row_bcast:15 -> rows 1,3
    v += dppmov<0x143, 0xc>(v);  // row_bcast:31 -> rows 2,3
    return v;                    // inclusive; lane63 = wave total
}

struct OutMap { unsigned char m[32]; };

typedef float v2f __attribute__((ext_vector_type(2)));

// ===========================================================================
// 256 threads x 16 elems/thread (T=4096), elems held as 8x float2.
// Per level L: [pre: products, fused inclusive cumsum chain -> dst slot,
// DPP wave scan, wave-total -> LDS] barrier [post: base = wex + carry,
// descending shift to exclusive] [root reduces at rlvl L]; final barrier.
// ===========================================================================
#define THREADS 256
#define VECN 8      // 8 x float2 = 16 elems
#define NWAVE 4

__global__ __launch_bounds__(THREADS) void fis_kernel(const float* __restrict__ x,
                                                      const float* __restrict__ alphas,
                                                      float* __restrict__ out,
                                                      const OutMap om) {
    using cx::PL;
    constexpr int NSER = PL.nser, NROOT = PL.nroot, NSLOT = PL.nslot, MAXL = PL.maxlvl;

    const int tid = threadIdx.x;
    const int lane = tid & 63;
    const int wv = tid >> 6;
    const int b = blockIdx.x >> 7;   // CH = 128
    const int c = blockIdx.x & 127;

    __shared__ float s_w[NSER + NROOT][NWAVE];

    v2f xr[VECN];
    {
        const float4* xv = reinterpret_cast<const float4*>(
            x + (((size_t)b << 7) + (size_t)c) * 4096 + (size_t)tid * 16);
#pragma unroll
        for (int j = 0; j < 4; ++j) {
            const float4 v = xv[j];
            xr[2 * j + 0] = v2f{v.x, v.y};
            xr[2 * j + 1] = v2f{v.z, v.w};
        }
    }

    v2f S[NSLOT][VECN];     // compile-time indexed after unroll -> registers
    float wex[cx::MAXSER];  // per-scan carried scalar (exclusive-in-wave offset)
    float tot[cx::MAXSER];

#pragma unroll
    for (int L = 0; L <= MAXL; ++L) {
        // ---- pre-phase: scans at level L ----
#pragma unroll
        for (int s = 0; s < NSER; ++s) {
            if (PL.lvl[s] != L) continue;
            const int ds = PL.slot[s];
            float run = 0.f;
            if (PL.nfac[s] == 0) {
                // leaf series: inclusive local cumsum of x (scalar chain, SSA)
#pragma unroll
                for (int j = 0; j < VECN; ++j) {
                    const float a = run + xr[j].x;
                    const float b2 = a + xr[j].y;
                    S[ds][j] = v2f{a, b2};
                    run = b2;
                }
            } else {
                v2f v[VECN];
#pragma unroll
                for (int j = 0; j < VECN; ++j) v[j] = xr[j];
#pragma unroll
                for (int k = 0; k < 3; ++k) {          // all factors but the last
                    if (k < PL.nfac[s] - 1) {
                        const int fs = PL.slot[PL.fac[s][k]];
#pragma unroll
                        for (int j = 0; j < VECN; ++j) v[j] *= S[fs][j];
                    }
                }
                const int fl = PL.slot[PL.fac[s][PL.nfac[s] - 1]];
#pragma unroll
                for (int j = 0; j < VECN; ++j) {       // fused scalar chain
                    const float a = __builtin_fmaf(v[j].x, S[fl][j].x, run);
                    const float b2 = __builtin_fmaf(v[j].y, S[fl][j].y, a);
                    S[ds][j] = v2f{a, b2};             // inclusive local
                    run = b2;
                }
            }
            tot[s] = run;
            const float wi = wave_incl_scan(run);
            if (lane == 63) s_w[s][wv] = wi;           // wave total
            wex[s] = wi - run;                         // exclusive within wave
        }
        __syncthreads();
        // ---- post-phase: exclusive = base + inclusive[j-1] (descending shift) ----
#pragma unroll
        for (int s = 0; s < NSER; ++s) {
            if (PL.lvl[s] != L) continue;
            const int ds = PL.slot[s];
            float base = wex[s];
#pragma unroll
            for (int k = 0; k < NWAVE - 1; ++k)
                if (k < wv) base += s_w[s][k];
#pragma unroll
            for (int j = VECN - 1; j >= 1; --j) {
                S[ds][j].y = base + S[ds][j].x;
                S[ds][j].x = base + S[ds][j - 1].y;
            }
            S[ds][0].y = base + S[ds][0].x;
            S[ds][0].x = base;
        }
        // ---- root reduces whose deepest factor is level L ----
#pragma unroll
        for (int r = 0; r < NROOT; ++r) {
            if (PL.rlvl[r] != L) continue;
            v2f v[VECN];
#pragma unroll
            for (int j = 0; j < VECN; ++j) v[j] = xr[j];
#pragma unroll
            for (int k = 0; k < 4; ++k) {              // all factors but the last
                if (k < PL.rnfac[r] - 1) {
                    const int fs = PL.slot[PL.rfac[r][k]];
#pragma unroll
                    for (int j = 0; j < VECN; ++j) v[j] *= S[fs][j];
                }
            }
            const int fl = PL.slot[PL.rfac[r][PL.rnfac[r] - 1]];
            v2f acc = v2f{0.f, 0.f};
#pragma unroll
            for (int j = 0; j < VECN; ++j) acc += v[j] * S[fl][j];  // packed fma
            const float wr = wave_incl_scan(acc.x + acc.y);
            if (lane == 63) s_w[NSER + r][wv] = wr;    // per-wave partial
        }
    }

    __syncthreads();
    if (tid < 32) {
        const int rid = om.m[tid];
        float T = 0.f;
#pragma unroll
        for (int k = 0; k < NWAVE; ++k) T += s_w[NSER + rid][k];
        const float* ap = alphas + tid * 768 + c;  // alphas[tree, i, c] : [32,6,128]
        const float aprod = ap[0] * ap[128] * ap[256] * ap[384] * ap[512] * ap[640];
        out[(((size_t)b << 5) + (size_t)tid) * 128 + c] = aprod * T;
    }
}

// ===========================================================================
extern "C" void kernel_launch(void* const* d_in, const int* in_sizes, int n_in,
                              void* d_out, int out_size, void* d_ws, size_t ws_size,
                              hipStream_t stream) {
    const float* x = (const float*)d_in[0];       // [16,128,4096] f32
    const float* alphas = (const float*)d_in[1];  // [32,6,128]    f32
    float* out = (float*)d_out;                   // [16,32,128]   f32

    OutMap om;
    for (int t = 0; t < cx::NTREE; ++t) om.m[t] = (unsigned char)cx::PL.tree_root[t];

    fis_kernel<<<dim3(16 * 128), dim3(THREADS), 0, stream>>>(x, alphas, out, om);
}